// Round 10
// baseline (1294.733 us; speedup 1.0000x reference)
//
#include <hip/hip_runtime.h>
#include <hip/hip_bf16.h>
#include <math.h>

// Problem constants
constexpr int Bn   = 32;
constexpr int Sn   = 256;
constexpr int Dn   = 512;
constexpr int Hn   = 8;
constexpr int DKn  = 64;
constexpr int Fn   = 2048;
constexpr int Ln   = 6;
constexpr int FEATn= 9;
constexpr int BSn  = Bn * Sn;          // 8192 rows

typedef __hip_bfloat16 bf16;
typedef __attribute__((ext_vector_type(8))) short short8;
typedef __attribute__((ext_vector_type(4))) short short4v;
typedef __attribute__((ext_vector_type(4))) float f32x4;

// global->LDS async copy, 16B per lane, LDS dest = wave-uniform base + lane*16
#define GLOAD_LDS16(gp, lp)                                                   \
    __builtin_amdgcn_global_load_lds(                                         \
        (const __attribute__((address_space(1))) void*)(gp),                  \
        (__attribute__((address_space(3))) void*)(lp), 16, 0, 0)

// raw barrier (NO implicit vmcnt drain) + compiler fences
#define BARRIER do {                                                          \
    __builtin_amdgcn_sched_barrier(0);                                        \
    asm volatile("" ::: "memory");                                            \
    __builtin_amdgcn_s_barrier();                                             \
    asm volatile("" ::: "memory");                                            \
    __builtin_amdgcn_sched_barrier(0);                                        \
} while (0)

#define VMCNT0 do {                                                           \
    asm volatile("s_waitcnt vmcnt(0)" ::: "memory");                          \
    __builtin_amdgcn_sched_barrier(0);                                        \
} while (0)

#define LGKM0 do {                                                            \
    asm volatile("s_waitcnt lgkmcnt(0)" ::: "memory");                        \
    __builtin_amdgcn_sched_barrier(0);                                        \
} while (0)

__device__ __forceinline__ short f2bs(float f) {
    __hip_bfloat16 h = __float2bfloat16(f);
    return *reinterpret_cast<short*>(&h);
}
__device__ __forceinline__ float bs2f(short s) {
    unsigned u = ((unsigned)(unsigned short)s) << 16;
    return *reinterpret_cast<float*>(&u);
}

// ---------------------------------------------------------------------------
// Embedding: x = (tgt*mask)@w_f2h + b_f2h + pos_emb + emb_time/gender/race
// ---------------------------------------------------------------------------
__global__ __launch_bounds__(256)
void k_embed(const float* __restrict__ tgt, const float* __restrict__ mask,
             const float* __restrict__ w_f2h, const float* __restrict__ b_f2h,
             const int* __restrict__ timei, const int* __restrict__ gender,
             const int* __restrict__ race,
             const float* __restrict__ emb_t, const float* __restrict__ emb_g,
             const float* __restrict__ emb_r, bf16* __restrict__ x)
{
    int idx = blockIdx.x * 256 + threadIdx.x;   // over BSn*Dn
    int d  = idx & (Dn - 1);
    int bs = idx >> 9;                           // /Dn
    int b  = bs / Sn;
    int s  = bs & (Sn - 1);
    const float* tg = tgt  + (size_t)bs * FEATn;
    const float* mk = mask + (size_t)bs * FEATn;
    float acc = b_f2h[d];
    #pragma unroll
    for (int f = 0; f < FEATn; ++f) acc += tg[f] * mk[f] * w_f2h[f * Dn + d];
    float phase = (float)s * expf(-((float)d / (float)Dn) * 9.210340372f); // ln(1e4)
    acc += (d & 1) ? cosf(phase) : sinf(phase);
    acc += emb_t[(size_t)timei[bs] * Dn + d];
    acc += emb_g[(size_t)gender[b] * Dn + d];
    acc += emb_r[(size_t)race[b]   * Dn + d];
    x[idx] = __float2bfloat16(acc);
}

// ---------------------------------------------------------------------------
// fp32 -> bf16 elementwise convert
// ---------------------------------------------------------------------------
__global__ __launch_bounds__(256)
void k_cvt(const float* __restrict__ in, bf16* __restrict__ out)
{
    int i = blockIdx.x * 256 + threadIdx.x;
    out[i] = __float2bfloat16(in[i]);
}

// ---------------------------------------------------------------------------
// Transpose + convert: in fp32 [B][R][C] -> out bf16 [B][C][R]
// Batched over up to 6 source/dest pairs: z in [0, 6*ZB); sel = z / ZB.
// ---------------------------------------------------------------------------
__global__ __launch_bounds__(256)
void k_tcvt6(const float* __restrict__ i0, bf16* __restrict__ o0,
             const float* __restrict__ i1, bf16* __restrict__ o1,
             const float* __restrict__ i2, bf16* __restrict__ o2,
             const float* __restrict__ i3, bf16* __restrict__ o3,
             const float* __restrict__ i4, bf16* __restrict__ o4,
             const float* __restrict__ i5, bf16* __restrict__ o5,
             int R, int C, int ZB)
{
    __shared__ float ts[32][33];
    const int sel = blockIdx.z / ZB, zi = blockIdx.z % ZB;
    const float* in  = sel == 0 ? i0 : sel == 1 ? i1 : sel == 2 ? i2
                     : sel == 3 ? i3 : sel == 4 ? i4 : i5;
    bf16*        out = sel == 0 ? o0 : sel == 1 ? o1 : sel == 2 ? o2
                     : sel == 3 ? o3 : sel == 4 ? o4 : o5;
    const int t  = threadIdx.x;
    const int tx = t & 31, ty = t >> 5;       // 8 rows per pass
    const int r0 = blockIdx.y * 32, c0 = blockIdx.x * 32;
    const size_t zo = (size_t)zi * R * C;
    #pragma unroll
    for (int i = 0; i < 4; ++i)
        ts[ty + 8 * i][tx] = in[zo + (size_t)(r0 + ty + 8 * i) * C + c0 + tx];
    __syncthreads();
    #pragma unroll
    for (int i = 0; i < 4; ++i)
        out[zo + (size_t)(c0 + ty + 8 * i) * R + r0 + tx] =
            __float2bfloat16(ts[tx][ty + 8 * i]);
}

// ---------------------------------------------------------------------------
// Prep for k_final2: Wcat bf16 [32][512] = concat(w_out^T, w_m^T, zero-pad),
// bcat fp32 [32] = concat(b_out, b_m, 0)
// ---------------------------------------------------------------------------
__global__ __launch_bounds__(256)
void k_prep_final(const float* __restrict__ w_out, const float* __restrict__ b_out,
                  const float* __restrict__ w_m, const float* __restrict__ b_m,
                  bf16* __restrict__ Wcat, float* __restrict__ bcat)
{
    int idx = blockIdx.x * 256 + threadIdx.x;   // 32*512
    int n = idx >> 9, k = idx & 511;
    float v = 0.f;
    if (n < FEATn)          v = w_out[(size_t)k * FEATn + n];
    else if (n < 2 * FEATn) v = w_m[(size_t)k * FEATn + (n - FEATn)];
    Wcat[idx] = __float2bfloat16(v);
    if (idx < 32) {
        float bv = idx < FEATn ? b_out[idx]
                 : (idx < 2 * FEATn ? b_m[idx - FEATn] : 0.f);
        bcat[idx] = bv;
    }
}

// ---------------------------------------------------------------------------
// 64xBN double-buffered prefetch 2-phase GEMM:
//   C[M,N] = (relu)(A[M,K] @ W[N,K]^T + bias) (+R residual)
// BK=64, 256 thr = 4 waves 2x2 (per-wave 32 x BN/2).  Per K-tile: {ds_read
// cur-buf frags || issue stage(next) into other buf -> lgkmcnt(0) -> MFMA ->
// vmcnt(0)+barrier}.  T2 chunk-XOR swizzle via pre-swizzled global source +
// swizzled ds_read.  Used for wo and ffn2.
// ---------------------------------------------------------------------------
template<int BN, bool RELU, bool RESID>
__global__ __launch_bounds__(256)
void k_gemm2ph(const bf16* __restrict__ Ain, const bf16* __restrict__ Win,
               const float* __restrict__ bia, const bf16* __restrict__ Rr,
               bf16* __restrict__ Cout, int M, int N, int K, int MTt, int NTt)
{
    constexpr int NT   = BN / 32;          // B frags per wave
    constexpr int NCB  = BN / 32;          // B staging calls (32 rows each)
    constexpr int BSZ  = BN * 64;          // B tile shorts
    constexpr int CSTR = BN + 8;           // epilogue row stride (shorts)
    constexpr int CPR  = BN / 8;           // 16B chunks per epilogue row
    __shared__ __align__(16) short smem[8192 + 2 * BSZ];

    // XCD swizzle: id&7 owns contiguous m-range (A-stationary)
    const int id = blockIdx.x;
    const int cx = id & 7, j = id >> 3;
    const int mt = cx * (MTt >> 3) + j / NTt;
    const int nt = j % NTt;
    const int m0 = mt * 64, n0 = nt * BN;

    const int t = threadIdx.x, w = t >> 6, lane = t & 63;
    const int l16 = lane & 15, quad = lane >> 4;
    const int wm = (w & 1) * 32, wn = (w >> 1) * (BN / 2);

    const short* A = (const short*)Ain;
    const short* W = (const short*)Win;

    // staging: 256 thr x 16B = 32 rows/call
    const int rowL = t >> 3;                     // 0..31
    const int cX   = (t & 7) ^ (rowL & 7);       // pre-swizzled k-chunk
    const short* pA0 = A + (size_t)(m0 +  0 + rowL) * K + cX * 8;
    const short* pA1 = A + (size_t)(m0 + 32 + rowL) * K + cX * 8;
    const short* pB[NCB];
    #pragma unroll
    for (int i = 0; i < NCB; ++i)
        pB[i] = W + (size_t)(n0 + i * 32 + rowL) * K + cX * 8;

    auto stage = [&](int nb, int k2) {
        short* dA = smem + nb * 4096 + t * 8;
        short* dB = smem + 8192 + nb * BSZ + t * 8;
        GLOAD_LDS16(pA0 + (size_t)k2 * 64, dA);
        GLOAD_LDS16(pA1 + (size_t)k2 * 64, dA + 2048);
        #pragma unroll
        for (int i = 0; i < NCB; ++i)
            GLOAD_LDS16(pB[i] + (size_t)k2 * 64, dB + i * 2048);
    };

    // fragment read bases (swizzled): addr = row*64 + ((chunk ^ (row&7))<<3)
    const int axor  = (quad ^ (l16 & 7)) << 3;
    const int aBase = (wm + l16) * 64 + axor;
    const int bBase = 8192 + (wn + l16) * 64 + axor;

    float bias_v[NT];
    #pragma unroll
    for (int ni = 0; ni < NT; ++ni)
        bias_v[ni] = bia[n0 + wn + ni * 16 + l16];

    f32x4 acc[2][NT] = {};

    stage(0, 0);
    VMCNT0;
    BARRIER;

    const int NKT = K >> 6;
    for (int kt = 0; kt < NKT; ++kt) {
        const int bufA = (kt & 1) * 4096;
        const int bufB = (kt & 1) * BSZ;
        short8 af[2][2], bw[2][NT];              // [ks][frag]
        #pragma unroll
        for (int mi = 0; mi < 2; ++mi) {
            const int a0 = bufA + aBase + mi * 1024;
            af[0][mi] = *(const short8*)(smem + a0);
            af[1][mi] = *(const short8*)(smem + (a0 ^ 32));  // ks=1: chunk^=4
        }
        #pragma unroll
        for (int ni = 0; ni < NT; ++ni) {
            const int b0 = bufB + bBase + ni * 1024;
            bw[0][ni] = *(const short8*)(smem + b0);
            bw[1][ni] = *(const short8*)(smem + (b0 ^ 32));
        }
        if (kt + 1 < NKT) stage((kt + 1) & 1, kt + 1);
        LGKM0;
        __builtin_amdgcn_s_setprio(1);
        #pragma unroll
        for (int ks = 0; ks < 2; ++ks)
            #pragma unroll
            for (int mi = 0; mi < 2; ++mi)
                #pragma unroll
                for (int ni = 0; ni < NT; ++ni)
                    acc[mi][ni] = __builtin_amdgcn_mfma_f32_16x16x32_bf16(
                        af[ks][mi], bw[ks][ni], acc[mi][ni], 0, 0, 0);
        __builtin_amdgcn_s_setprio(0);
        VMCNT0;
        BARRIER;
    }

    // epilogue: stage [64][CSTR] in smem, coalesced b128 stores
    #pragma unroll
    for (int mi = 0; mi < 2; ++mi)
        #pragma unroll
        for (int ni = 0; ni < NT; ++ni)
            #pragma unroll
            for (int r = 0; r < 4; ++r) {
                float v = acc[mi][ni][r] + bias_v[ni];
                if (RELU) v = fmaxf(v, 0.f);
                smem[(wm + mi * 16 + quad * 4 + r) * CSTR
                     + wn + ni * 16 + l16] = f2bs(v);
            }
    LGKM0;
    BARRIER;
    #pragma unroll
    for (int cc = 0; cc < 64 * CPR; cc += 256) {
        const int idx = cc + t;
        const int row = idx / CPR, colc = idx % CPR;
        const size_t goff = (size_t)(m0 + row) * N + n0 + colc * 8;
        short8 cv = *(const short8*)(smem + row * CSTR + colc * 8);
        if (RESID) {
            short8 rv = *(const short8*)((const short*)Rr + goff);
            short8 ov;
            #pragma unroll
            for (int i = 0; i < 8; ++i)
                ov[i] = f2bs(bs2f(cv[i]) + bs2f(rv[i]));
            *(short8*)((short*)Cout + goff) = ov;
        } else {
            *(short8*)((short*)Cout + goff) = cv;
        }
    }
}

// ---------------------------------------------------------------------------
// Shared 8-phase compute phase: ds-read one C-quadrant's fragments (swizzled),
// issue staging, barrier, lgkm-drain, setprio-wrapped 16 MFMA, barrier.
// ---------------------------------------------------------------------------
template<int RH, int CH, class STG, class FIN>
__device__ __forceinline__ void gemm8_phase(short* sm, int buf, int baseA,
                                            int baseB, f32x4 (&acc)[8][4],
                                            STG stg, FIN fin)
{
    short8 paf[2][4];
    short8 pbf[2][2];
    #pragma unroll
    for (int i = 0; i < 4; ++i) {
        const int a0 = buf + baseA + RH * 4096 + i * 1024;
        paf[0][i] = *(const short8*)(sm + a0);
        paf[1][i] = *(const short8*)(sm + (a0 ^ 32));   // ks=1: chunk ^= 4
    }
    #pragma unroll
    for (int j = 0; j < 2; ++j) {
        const int b0 = buf + baseB + CH * 2048 + j * 1024;
        pbf[0][j] = *(const short8*)(sm + b0);
        pbf[1][j] = *(const short8*)(sm + (b0 ^ 32));
    }
    stg();
    BARRIER;
    __builtin_amdgcn_s_setprio(1);
    #pragma unroll
    for (int i = 0; i < 4; ++i)
        #pragma unroll
        for (int j = 0; j < 2; ++j) {
            acc[RH * 4 + i][CH * 2 + j] = __builtin_amdgcn_mfma_f32_16x16x32_bf16(
                paf[0][i], pbf[0][j], acc[RH * 4 + i][CH * 2 + j], 0, 0, 0);
            acc[RH * 4 + i][CH * 2 + j] = __builtin_amdgcn_mfma_f32_16x16x32_bf16(
                paf[1][i], pbf[1][j], acc[RH * 4 + i][CH * 2 + j], 0, 0, 0);
        }
    __builtin_amdgcn_s_setprio(0);
    fin();
    BARRIER;
}

// ---------------------------------------------------------------------------
// 256x256 8-phase bf16 GEMM (T2 swizzle + T3/T4 counted-wait phases + T5
// setprio).  C[M,N] = relu(A[M,K] @ W[N,K]^T + bias).  512 thr = 8 waves
// (2M x 4N), per-wave 128x64, BK=64, LDS 128 KiB dbuf.  Used for ffn1.
// ---------------------------------------------------------------------------
template<bool RELU>
__global__ __launch_bounds__(512, 2)
void k_gemm8ph(const bf16* __restrict__ Ain, const bf16* __restrict__ Win,
               const float* __restrict__ bia, bf16* __restrict__ Cout,
               int M, int N, int K, int NTt)
{
    __shared__ __align__(16) short smem[65536];   // 128 KiB: A 64K | B 64K

    // ---- XCD swizzle decode (A-stationary: id&7 owns contiguous m-range) --
    const int id  = blockIdx.x;
    const int cxd = id & 7, jj = id >> 3;
    const int mpx = (M >> 8) >> 3;                // (M/256)/8
    const int ml  = jj / NTt, nl = jj % NTt;
    const int mt  = cxd * mpx + ml;
    const int m0  = mt * 256, n0 = nl * 256;

    const int t    = threadIdx.x;
    const int lane = t & 63, w = t >> 6;
    const int l16  = lane & 15, quad = lane >> 4;
    const int wr   = w >> 2, wc = w & 3;          // wave grid 2M x 4N

    const short* A = (const short*)Ain;
    const short* W = (const short*)Win;

    // ---- staging geometry (per-thread, both halves x both passes) --------
    const int rowL = t >> 3;                      // 0..63
    const int cX   = (t & 7) ^ (rowL & 7);        // pre-swizzled k-chunk
    const short* pA00 = A + (size_t)(m0 +   0 +  0 + rowL) * K + cX * 8;
    const short* pA01 = A + (size_t)(m0 +   0 + 64 + rowL) * K + cX * 8;
    const short* pA10 = A + (size_t)(m0 + 128 +  0 + rowL) * K + cX * 8;
    const short* pA11 = A + (size_t)(m0 + 128 + 64 + rowL) * K + cX * 8;
    const short* pB00 = W + (size_t)(n0 +   0 +  0 + rowL) * K + cX * 8;
    const short* pB01 = W + (size_t)(n0 +   0 + 64 + rowL) * K + cX * 8;
    const short* pB10 = W + (size_t)(n0 + 128 +  0 + rowL) * K + cX * 8;
    const short* pB11 = W + (size_t)(n0 + 128 + 64 + rowL) * K + cX * 8;

    auto stageA = [&](int nb, int k2) {
        short* d = smem + nb * 16384 + t * 8;
        GLOAD_LDS16(pA00 + (size_t)k2 * 64, d);
        GLOAD_LDS16(pA01 + (size_t)k2 * 64, d + 4096);
        GLOAD_LDS16(pA10 + (size_t)k2 * 64, d + 8192);
        GLOAD_LDS16(pA11 + (size_t)k2 * 64, d + 12288);
    };
    auto stageB = [&](int nb, int k2) {
        short* d = smem + 32768 + nb * 16384 + t * 8;
        GLOAD_LDS16(pB00 + (size_t)k2 * 64, d);
        GLOAD_LDS16(pB01 + (size_t)k2 * 64, d + 4096);
        GLOAD_LDS16(pB10 + (size_t)k2 * 64, d + 8192);
        GLOAD_LDS16(pB11 + (size_t)k2 * 64, d + 12288);
    };

    // ---- fragment read bases (swizzled; A-half = wr, B-half = wc>>1) -----
    const int axor  = (quad ^ (l16 & 7)) << 3;
    const int baseA = wr * 8192 + l16 * 64 + axor;
    const int baseB = 32768 + (wc >> 1) * 8192 + (wc & 1) * 4096
                    + l16 * 64 + axor;

    float bias_v[4];
    #pragma unroll
    for (int ni = 0; ni < 4; ++ni)
        bias_v[ni] = bia[n0 + wc * 64 + ni * 16 + l16];

    f32x4 acc[8][4] = {};

    // ---- prologue: stage tile 0 fully ------------------------------------
    stageA(0, 0);
    stageB(0, 0);
    VMCNT0;
    BARRIER;

    const int NKT = K >> 6;
    for (int kt = 0; kt < NKT; ++kt) {
        const int  buf = (kt & 1) << 14;          // *16384 shorts
        const int  nb  = (kt + 1) & 1;
        const bool st  = (kt + 1) < NKT;
        gemm8_phase<0, 0>(smem, buf, baseA, baseB, acc,
                          [&] { if (st) stageA(nb, kt + 1); }, [&] {});
        gemm8_phase<0, 1>(smem, buf, baseA, baseB, acc,
                          [&] { if (st) stageB(nb, kt + 1); }, [&] {});
        gemm8_phase<1, 0>(smem, buf, baseA, baseB, acc, [&] {}, [&] {});
        gemm8_phase<1, 1>(smem, buf, baseA, baseB, acc, [&] {}, [&] { VMCNT0; });
    }

    // ---- epilogue: 2 row-half passes through LDS, coalesced b128 stores --
    #pragma unroll
    for (int p = 0; p < 2; ++p) {
        if (wr == p) {
            #pragma unroll
            for (int mi = 0; mi < 8; ++mi)
                #pragma unroll
                for (int ni = 0; ni < 4; ++ni)
                    #pragma unroll
                    for (int r = 0; r < 4; ++r) {
                        float v = acc[mi][ni][r] + bias_v[ni];
                        if (RELU) v = fmaxf(v, 0.f);
                        smem[(mi * 16 + quad * 4 + r) * 264
                             + wc * 64 + ni * 16 + l16] = f2bs(v);
                    }
        }
        LGKM0;
        BARRIER;
        #pragma unroll
        for (int i2 = 0; i2 < 8; ++i2) {
            const int idx = i2 * 512 + t;
            const int row = idx >> 5, chn = idx & 31;
            short8 cv = *(const short8*)(smem + row * 264 + chn * 8);
            *(short8*)((short*)Cout + (size_t)(m0 + p * 128 + row) * N
                                     + n0 + chn * 8) = cv;
        }
        LGKM0;
        BARRIER;
    }
}

// ---------------------------------------------------------------------------
// Fused QKV projection as one 256x256 8-phase GEMM over virtual N = 1536.
// 32 m-tiles x 6 n-tiles = 192 wgs; sel = nl>>1 picks {q,k,v} weight/bias/
// output (and A operand: q,k from Aqk, v from Av -- differs for cross-attn).
// sel<2: standard epilogue into Cq/Ck [8192][512] at col (nl&1)*256.
// sel==2: TRANSPOSED epilogue into Vt [512][8192] (what k_attn_mfma needs),
// 4 passes of 64 n-rows staged [64][264] in LDS, coalesced 16B stores.
// ---------------------------------------------------------------------------
__global__ __launch_bounds__(512, 2)
void k_qkv8ph(const bf16* __restrict__ Aqk, const bf16* __restrict__ Av,
              const bf16* __restrict__ Wq, const bf16* __restrict__ Wk,
              const bf16* __restrict__ Wv,
              const float* __restrict__ bq, const float* __restrict__ bk,
              const float* __restrict__ bv,
              bf16* __restrict__ Cq, bf16* __restrict__ Ck,
              bf16* __restrict__ Vt)
{
    __shared__ __align__(16) short smem[65536];   // 128 KiB

    constexpr int K = Dn;                          // 512
    // ---- decode: cxd owns 4 contiguous m-tiles, iterates 6 n-tiles -------
    const int id  = blockIdx.x;                    // 0..191
    const int cxd = id & 7, jj = id >> 3;          // jj 0..23
    const int ml  = jj / 6, nl = jj % 6;
    const int mt  = cxd * 4 + ml;
    const int m0  = mt * 256;
    const int sel = nl >> 1;                       // 0=q 1=k 2=v
    const int n0l = (nl & 1) * 256;                // col offset in 512-wide out

    const short* A = (const short*)(sel < 2 ? Aqk : Av);
    const short* W = (const short*)(sel == 0 ? Wq : sel == 1 ? Wk : Wv);
    const float* bia = sel == 0 ? bq : sel == 1 ? bk : bv;

    const int t    = threadIdx.x;
    const int lane = t & 63, w = t >> 6;
    const int l16  = lane & 15, quad = lane >> 4;
    const int wr   = w >> 2, wc = w & 3;

    // ---- staging geometry ------------------------------------------------
    const int rowL = t >> 3;
    const int cX   = (t & 7) ^ (rowL & 7);
    const short* pA00 = A + (size_t)(m0 +   0 +  0 + rowL) * K + cX * 8;
    const short* pA01 = A + (size_t)(m0 +   0 + 64 + rowL) * K + cX * 8;
    const short* pA10 = A + (size_t)(m0 + 128 +  0 + rowL) * K + cX * 8;
    const short* pA11 = A + (size_t)(m0 + 128 + 64 + rowL) * K + cX * 8;
    const short* pB00 = W + (size_t)(n0l +   0 +  0 + rowL) * K + cX * 8;
    const short* pB01 = W + (size_t)(n0l +   0 + 64 + rowL) * K + cX * 8;
    const short* pB10 = W + (size_t)(n0l + 128 +  0 + rowL) * K + cX * 8;
    const short* pB11 = W + (size_t)(n0l + 128 + 64 + rowL) * K + cX * 8;

    auto stageA = [&](int nb, int k2) {
        short* d = smem + nb * 16384 + t * 8;
        GLOAD_LDS16(pA00 + (size_t)k2 * 64, d);
        GLOAD_LDS16(pA01 + (size_t)k2 * 64, d + 4096);
        GLOAD_LDS16(pA10 + (size_t)k2 * 64, d + 8192);
        GLOAD_LDS16(pA11 + (size_t)k2 * 64, d + 12288);
    };
    auto stageB = [&](int nb, int k2) {
        short* d = smem + 32768 + nb * 16384 + t * 8;
        GLOAD_LDS16(pB00 + (size_t)k2 * 64, d);
        GLOAD_LDS16(pB01 + (size_t)k2 * 64, d + 4096);
        GLOAD_LDS16(pB10 + (size_t)k2 * 64, d + 8192);
        GLOAD_LDS16(pB11 + (size_t)k2 * 64, d + 12288);
    };

    const int axor  = (quad ^ (l16 & 7)) << 3;
    const int baseA = wr * 8192 + l16 * 64 + axor;
    const int baseB = 32768 + (wc >> 1) * 8192 + (wc & 1) * 4096
                    + l16 * 64 + axor;

    float bias_v[4];
    #pragma unroll
    for (int ni = 0; ni < 4; ++ni)
        bias_v[ni] = bia[n0l + wc * 64 + ni * 16 + l16];

    f32x4 acc[8][4] = {};

    stageA(0, 0);
    stageB(0, 0);
    VMCNT0;
    BARRIER;

    constexpr int NKT = K >> 6;                   // 8
    for (int kt = 0; kt < NKT; ++kt) {
        const int  buf = (kt & 1) << 14;
        const int  nb  = (kt + 1) & 1;
        const bool st  = (kt + 1) < NKT;
        gemm8_phase<0, 0>(smem, buf, baseA, baseB, acc,
                          [&] { if (st) stageA(nb, kt + 1); }, [&] {});
        gemm8_phase<0, 1>(smem, buf, baseA, baseB, acc,
                          [&] { if (st) stageB(nb, kt + 1); }, [&] {});
        gemm8_phase<1, 0>(smem, buf, baseA, baseB, acc, [&] {}, [&] {});
        gemm8_phase<1, 1>(smem, buf, baseA, baseB, acc, [&] {}, [&] { VMCNT0; });
    }

    if (sel < 2) {
        bf16* C = sel == 0 ? Cq : Ck;
        #pragma unroll
        for (int p = 0; p < 2; ++p) {
            if (wr == p) {
                #pragma unroll
                for (int mi = 0; mi < 8; ++mi)
                    #pragma unroll
                    for (int ni = 0; ni < 4; ++ni)
                        #pragma unroll
                        for (int r = 0; r < 4; ++r)
                            smem[(mi * 16 + quad * 4 + r) * 264
                                 + wc * 64 + ni * 16 + l16] =
                                f2bs(acc[mi][ni][r] + bias_v[ni]);
            }
            LGKM0;
            BARRIER;
            #pragma unroll
            for (int i2 = 0; i2 < 8; ++i2) {
                const int idx = i2 * 512 + t;
                const int row = idx >> 5, chn = idx & 31;
                short8 cv = *(const short8*)(smem + row * 264 + chn * 8);
                *(short8*)((short*)C + (size_t)(m0 + p * 128 + row) * Dn
                                     + n0l + chn * 8) = cv;
            }
            LGKM0;
            BARRIER;
        }
    } else {
        // transposed epilogue: Vt[n0l + n][m0 + m], 4 passes of 64 n-rows
        #pragma unroll
        for (int p = 0; p < 4; ++p) {
            if (wc == p) {
                #pragma unroll
                for (int mi = 0; mi < 8; ++mi)
                    #pragma unroll
                    for (int ni = 0; ni < 4; ++ni)
                        #pragma unroll
                        for (int r = 0; r < 4; ++r)
                            smem[(ni * 16 + l16) * 264
                                 + wr * 128 + mi * 16 + quad * 4 + r] =
                                f2bs(acc[mi][ni][r] + bias_v[ni]);
            }
            LGKM0;
            BARRIER;
            #pragma unroll
            for (int i2 = 0; i2 < 4; ++i2) {
                const int idx = i2 * 512 + t;
                const int row = idx >> 5, chn = idx & 31;   // row<64, chn<32
                short8 cv = *(const short8*)(smem + row * 264 + chn * 8);
                *(short8*)((short*)Vt + (size_t)(n0l + p * 64 + row) * BSn
                                      + m0 + chn * 8) = cv;
            }
            LGKM0;
            BARRIER;
        }
    }
}

// ---------------------------------------------------------------------------
// MFMA attention, stage-once per (b,h).  q,k in [B,S,H*DK]; vT in
// [H*DK][B*S]; out in [B,S,H*DK].  Block = (b,h): 1024 thr = 16 waves, each
// wave owns 16 q-rows.  Grid = 256 = exact 1 block/CU.  K (32KB) + V (32KB)
// staged ONCE; P in per-wave PRIVATE 16x128 LDS slices (64KB, chunk-XOR
// swizzled), two 128-key halves reuse the slice -> ONE __syncthreads().
// ---------------------------------------------------------------------------
__global__ __launch_bounds__(1024)
void k_attn_mfma(const bf16* __restrict__ q, const bf16* __restrict__ k,
                 const bf16* __restrict__ vT, bf16* __restrict__ ocat)
{
    __shared__ __align__(16) short smem[65536];   // 128 KiB
    short* Vst = smem;            // [64 dv][256 key], 16B chunks XOR-swizzled
    short* Ks  = smem + 16384;    // [256 key][64 dk], 16B chunks XOR-swizzled
    short* Ps  = smem + 32768;    // 16 x per-wave [16 q][128 k] slices

    const int t = threadIdx.x, w = t >> 6, lane = t & 63;
    const int l16 = lane & 15, quad = lane >> 4;
    const int bh = blockIdx.x;
    const int h  = bh & 7;
    const int b  = bh >> 3;

    const short* kg = (const short*)k  + (size_t)b * Sn * Dn + h * DKn;
    const short* qg = (const short*)q  + (size_t)b * Sn * Dn + h * DKn;
    const short* vg = (const short*)vT + (size_t)h * DKn * BSn + b * Sn;

    #pragma unroll
    for (int i = 0; i < 2; ++i) {
        const int c   = i * 1024 + w * 64 + lane;
        const int key = c >> 3, cgk = (c & 7) ^ (key & 7);
        GLOAD_LDS16(kg + (size_t)key * Dn + cgk * 8, Ks + (i * 1024 + w * 64) * 8);
        const int dv = c >> 5, cgv = (c & 31) ^ (dv & 7);
        GLOAD_LDS16(vg + (size_t)dv * BSn + cgv * 8, Vst + (i * 1024 + w * 64) * 8);
    }

    const short* qp = qg + (size_t)(w * 16 + l16) * Dn + quad * 8;
    short8 bq0 = *(const short8*)(qp);
    short8 bq1 = *(const short8*)(qp + 32);
    __syncthreads();    // drains vmcnt (K/V landed); the ONLY barrier

    // ---- S^T = K @ Q^T : per-lane 64 scores of q-row l16 ----
    f32x4 accs[16];
    #pragma unroll
    for (int mi = 0; mi < 16; ++mi) accs[mi] = f32x4{0.f, 0.f, 0.f, 0.f};
    #pragma unroll
    for (int mi = 0; mi < 16; ++mi) {
        const int key = mi * 16 + l16;
        const int r0s = (quad     ^ (key & 7)) * 8;
        const int r1s = ((quad+4) ^ (key & 7)) * 8;
        short8 af0 = *(const short8*)(Ks + key * 64 + r0s);
        short8 af1 = *(const short8*)(Ks + key * 64 + r1s);
        accs[mi] = __builtin_amdgcn_mfma_f32_16x16x32_bf16(af0, bq0, accs[mi], 0, 0, 0);
        accs[mi] = __builtin_amdgcn_mfma_f32_16x16x32_bf16(af1, bq1, accs[mi], 0, 0, 0);
    }

    // ---- softmax over keys (reduce across quad groups) ----
    float mx = -1e30f;
    #pragma unroll
    for (int mi = 0; mi < 16; ++mi)
        #pragma unroll
        for (int r = 0; r < 4; ++r) mx = fmaxf(mx, accs[mi][r]);
    mx = fmaxf(mx, __shfl_xor(mx, 16));
    mx = fmaxf(mx, __shfl_xor(mx, 32));
    float sum = 0.f;
    #pragma unroll
    for (int mi = 0; mi < 16; ++mi)
        #pragma unroll
        for (int r = 0; r < 4; ++r) {
            float e = __expf((accs[mi][r] - mx) * 0.125f);
            accs[mi][r] = e;
            sum += e;
        }
    sum += __shfl_xor(sum, 16);
    sum += __shfl_xor(sum, 32);
    const float rs = 1.f / sum;

    // ---- P -> private LDS slice, PV in two 128-key halves ----
    short* pr = Ps + w * 2048 + l16 * 128;        // this wave, this q-row
    const int psw = (l16 & 7) << 3;               // chunk-XOR swizzle

    f32x4 acco[4];
    #pragma unroll
    for (int nt = 0; nt < 4; ++nt) acco[nt] = f32x4{0.f, 0.f, 0.f, 0.f};

    #pragma unroll
    for (int half = 0; half < 2; ++half) {
        if (half) LGKM0;                          // slice reads done before reuse
        #pragma unroll
        for (int mi = 0; mi < 8; ++mi) {
            const int mg = half * 8 + mi;
            short4v pk;
            pk.x = f2bs(accs[mg][0] * rs);
            pk.y = f2bs(accs[mg][1] * rs);
            pk.z = f2bs(accs[mg][2] * rs);
            pk.w = f2bs(accs[mg][3] * rs);
            *(short4v*)(pr + ((mi * 16 + quad * 4) ^ psw)) = pk;
        }
        LGKM0;                                    // writes visible to own reads
        #pragma unroll
        for (int k0 = 0; k0 < 4; ++k0) {
            short8 pa = *(const short8*)(pr + ((k0 * 32 + quad * 8) ^ psw));
            #pragma unroll
            for (int nt = 0; nt < 4; ++nt) {
                const int dv = nt * 16 + l16;
                const int ch = 4 * (half * 4 + k0) + quad;
                const int sl = (ch ^ (dv & 7)) * 8;
                short8 vb = *(const short8*)(Vst + dv * 256 + sl);
                acco[nt] = __builtin_amdgcn_mfma_f32_16x16x32_bf16(
                    pa, vb, acco[nt], 0, 0, 0);
            }
        }
    }

    // ---- epilogue: reuse own slice as [16 q][72] staging, b128 stores ----
    LGKM0;                                        // PV reads done before overlay
    short* cs = Ps + w * 2048;
    #pragma unroll
    for (int nt = 0; nt < 4; ++nt)
        #pragma unroll
        for (int r = 0; r < 4; ++r)
            cs[(quad * 4 + r) * 72 + nt * 16 + l16] = f2bs(acco[nt][r]);
    LGKM0;
    #pragma unroll
    for (int j = 0; j < 2; ++j) {
        const int idx = j * 64 + lane;
        const int row = idx >> 3, colc = idx & 7;
        short8 cv = *(const short8*)(cs + row * 72 + colc * 8);
        *(short8*)((short*)ocat + (size_t)(b * Sn + w * 16 + row) * Dn
                                 + h * DKn + colc * 8) = cv;
    }
}

// ---------------------------------------------------------------------------
// LayerNorm over D=512: one wave per row, b128 loads, shfl-only reduction.
// ---------------------------------------------------------------------------
__global__ __launch_bounds__(256)
void k_ln(const bf16* __restrict__ y, const float* __restrict__ g,
          const float* __restrict__ be, bf16* __restrict__ xo)
{
    const int t = threadIdx.x, w = t >> 6, lane = t & 63;
    const int row = blockIdx.x * 4 + w;
    const short* yr = (const short*)y + (size_t)row * Dn + lane * 8;
    short8 v8 = *(const short8*)yr;
    float f[8];
    float s1 = 0.f, s2 = 0.f;
    #pragma unroll
    for (int i = 0; i < 8; ++i) {
        f[i] = bs2f(v8[i]);
        s1 += f[i];
        s2 += f[i] * f[i];
    }
    #pragma unroll
    for (int off = 1; off < 64; off <<= 1) {
        s1 += __shfl_xor(s1, off);
        s2 += __shfl_xor(s2, off);
    }
    const float mean = s1 * (1.f / Dn);
    const float var  = s2 * (1.f / Dn) - mean * mean;
    const float isd  = rsqrtf(var + 1e-5f);
    const float4 g0 = *(const float4*)(g  + lane * 8);
    const float4 g1 = *(const float4*)(g  + lane * 8 + 4);
    const float4 b0 = *(const float4*)(be + lane * 8);
    const float4 b1 = *(const float4*)(be + lane * 8 + 4);
    const float gg[8] = {g0.x, g0.y, g0.z, g0.w, g1.x, g1.y, g1.z, g1.w};
    const float bb[8] = {b0.x, b0.y, b0.z, b0.w, b1.x, b1.y, b1.z, b1.w};
    short8 o8;
    #pragma unroll
    for (int i = 0; i < 8; ++i)
        o8[i] = f2bs((f[i] - mean) * isd * gg[i] + bb[i]);
    *(short8*)((short*)xo + (size_t)row * Dn + lane * 8) = o8;
}

// ---------------------------------------------------------------------------
// Final head as skinny MFMA GEMM: out = sigmoid(X @ Wcat^T + bcat).
// ---------------------------------------------------------------------------
__global__ __launch_bounds__(256)
void k_final2(const bf16* __restrict__ x, const bf16* __restrict__ Wcat,
              const float* __restrict__ bcat, const int* __restrict__ timei,
              float* __restrict__ out)
{
    const int t = threadIdx.x, w = t >> 6, lane = t & 63;
    const int l16 = lane & 15, quad = lane >> 4;
    const int r0 = blockIdx.x * 64 + w * 16;
    const short* xp = (const short*)x + (size_t)(r0 + l16) * Dn + quad * 8;
    const short* wp = (const short*)Wcat + (size_t)l16 * Dn + quad * 8;

    f32x4 acc[2] = {};
    #pragma unroll
    for (int kk = 0; kk < 16; ++kk) {
        short8 af = *(const short8*)(xp + kk * 32);
        short8 b0 = *(const short8*)(wp + kk * 32);
        short8 b1 = *(const short8*)(wp + 16 * Dn + kk * 32);
        acc[0] = __builtin_amdgcn_mfma_f32_16x16x32_bf16(af, b0, acc[0], 0, 0, 0);
        acc[1] = __builtin_amdgcn_mfma_f32_16x16x32_bf16(af, b1, acc[1], 0, 0, 0);
    }

    #pragma unroll
    for (int nt = 0; nt < 2; ++nt) {
        const int col = nt * 16 + l16;
        const float bb = bcat[col];
        #pragma unroll
        for (int r = 0; r < 4; ++r) {
            const int row = r0 + quad * 4 + r;
            float v = acc[nt][r] + bb;
            float sg = 1.f / (1.f + expf(-v));
            if (col < FEATn)
                out[(size_t)row * FEATn + col] = sg;
            else if (col < 2 * FEATn)
                out[(size_t)BSn * FEATn + BSn + (size_t)row * FEATn + (col - FEATn)] = sg;
        }
    }
    if (l16 == 0) {
        #pragma unroll
        for (int r = 0; r < 4; ++r) {
            const int row = r0 + quad * 4 + r;
            out[(size_t)BSn * FEATn + row] = (float)timei[row];
        }
    }
}

// ---------------------------------------------------------------------------
extern "C" void kernel_launch(void* const* d_in, const int* in_sizes, int n_in,
                              void* d_out, int out_size, void* d_ws, size_t ws_size,
                              hipStream_t stream)
{
    const float* tgt    = (const float*)d_in[0];
    const float* memory = (const float*)d_in[1];
    const int*   timei  = (const int*)  d_in[2];
    const int*   gender = (const int*)  d_in[3];
    const int*   race   = (const int*)  d_in[4];
    const float* maskp  = (const float*)d_in[5];
    const float* w_f2h  = (const float*)d_in[6];
    const float* b_f2h  = (const float*)d_in[7];
    const float* emb_t  = (const float*)d_in[8];
    const float* emb_g  = (const float*)d_in[9];
    const float* emb_r  = (const float*)d_in[10];
    const float* wq1 = (const float*)d_in[11]; const float* bq1 = (const float*)d_in[12];
    const float* wk1 = (const float*)d_in[13]; const float* bk1 = (const float*)d_in[14];
    const float* wv1 = (const float*)d_in[15]; const float* bv1 = (const float*)d_in[16];
    const float* wo1 = (const float*)d_in[17]; const float* bo1 = (const float*)d_in[18];
    const float* g1  = (const float*)d_in[19]; const float* be1 = (const float*)d_in[20];
    const float* wq2 = (const float*)d_in[21]; const float* bq2 = (const float*)d_in[22];
    const float* wk2 = (const float*)d_in[23]; const float* bk2 = (const float*)d_in[24];
    const float* wv2 = (const float*)d_in[25]; const float* bv2 = (const float*)d_in[26];
    const float* wo2 = (const float*)d_in[27]; const float* bo2 = (const float*)d_in[28];
    const float* g2  = (const float*)d_in[29]; const float* be2 = (const float*)d_in[30];
    const float* w1f = (const float*)d_in[31]; const float* b1f = (const float*)d_in[32];
    const float* w2f = (const float*)d_in[33]; const float* b2f = (const float*)d_in[34];
    const float* gfp = (const float*)d_in[35]; const float* bff = (const float*)d_in[36];
    const float* w_out = (const float*)d_in[37]; const float* b_out = (const float*)d_in[38];
    const float* w_m   = (const float*)d_in[39]; const float* b_m   = (const float*)d_in[40];
    float* out = (float*)d_out;

    // ---- workspace layout (bf16 elems) ----
    constexpr size_t WH  = 1572864;            // headed / wo per-array
    constexpr size_t WF  = 6291456;            // w1f / w2f per-array
    constexpr size_t NA  = (size_t)BSn * Dn;   // activation elems
    bf16* wsb   = (bf16*)d_ws;
    bf16* wq1t  = wsb;
    bf16* wk1t  = wq1t + WH;
    bf16* wv1t  = wk1t + WH;
    bf16* wo1t  = wv1t + WH;
    bf16* wq2t  = wo1t + WH;
    bf16* wk2t  = wq2t + WH;
    bf16* wv2t  = wk2t + WH;
    bf16* wo2t  = wv2t + WH;
    bf16* w1ft  = wo2t + WH;
    bf16* w2ft  = w1ft + WF;
    bf16* memb  = w2ft + WF;
    bf16* x     = memb + NA;
    bf16* b1    = x  + NA;
    bf16* b2    = b1 + NA;
    bf16* b3    = b2 + NA;     // Vt [512][8192] from v-proj transposed epilogue
    bf16* b4    = b3 + NA;
    bf16* h1    = b1;          // [8192][2048] spans b1..b4
    bf16* wcat  = b4 + NA;     // [32][512]
    float* bcat = (float*)(wcat + 32 * Dn);

    dim3 blk(256);

    // ---- weight transpose+convert (batched) ----
    k_tcvt6<<<dim3( 2, 16, 288), blk, 0, stream>>>(
        wq1, wq1t, wk1, wk1t, wv1, wv1t, wq2, wq2t, wk2, wk2t, wv2, wv2t,
        512, 64, 48);
    k_tcvt6<<<dim3(16, 16, 12), blk, 0, stream>>>(
        wo1, wo1t, wo2, wo2t, wo1, wo1t, wo1, wo1t, wo1, wo1t, wo1, wo1t,
        512, 512, 6);
    k_tcvt6<<<dim3(64, 16, 6), blk, 0, stream>>>(
        w1f, w1ft, w1f, w1ft, w1f, w1ft, w1f, w1ft, w1f, w1ft, w1f, w1ft,
        512, 2048, 6);
    k_tcvt6<<<dim3(16, 64, 6), blk, 0, stream>>>(
        w2f, w2ft, w2f, w2ft, w2f, w2ft, w2f, w2ft, w2f, w2ft, w2f, w2ft,
        2048, 512, 6);
    k_cvt <<<dim3(NA / 256), blk, 0, stream>>>(memory, memb);
    k_prep_final<<<dim3(64), blk, 0, stream>>>(w_out, b_out, w_m, b_m, wcat, bcat);

    k_embed<<<dim3((BSn * Dn) / 256), blk, 0, stream>>>(
        tgt, maskp, w_f2h, b_f2h, timei, gender, race, emb_t, emb_g, emb_r, x);

    // grids
    dim3 gQ (192);            // qkv 8-phase: 32 m-tiles x 6 n-tiles
    dim3 gW (128 * 4);        // wo / ffn2 2-phase 64x128: MT=128, NT=4
    dim3 g8 (32 * 8);         // ffn1 8-phase 256x256: (M/256)*(N/256) = 256 wgs
    dim3 blk8(512);
    dim3 gA (Bn * Hn);        // attn: one 1024-thr block per (b,h), 1/CU
    dim3 blkA(1024);
    dim3 gL (BSn / 4);
    constexpr size_t WSL = 262144;
    constexpr size_t WFL = 1048576;

    for (int l = 0; l < Ln; ++l) {
        // ---- self-attention ----
        k_qkv8ph<<<gQ, blk8, 0, stream>>>(
            x, x,
            wq1t + l * WSL, wk1t + l * WSL, wv1t + l * WSL,
            bq1 + l * Dn, bk1 + l * Dn, bv1 + l * Dn,
            b1, b2, b3);
        k_attn_mfma<<<gA, blkA, 0, stream>>>(b1, b2, b3, b4);
        k_gemm2ph<128, false, true><<<gW, blk, 0, stream>>>(
            b4, wo1t + l * WSL, bo1 + l * Dn, x, x, BSn, Dn, Dn, 128, 4);
        k_ln<<<gL, blk, 0, stream>>>(x, g1 + l * Dn, be1 + l * Dn, x);
        // ---- cross block: q,k from memory; v from x ----
        k_qkv8ph<<<gQ, blk8, 0, stream>>>(
            memb, x,
            wq2t + l * WSL, wk2t + l * WSL, wv2t + l * WSL,
            bq2 + l * Dn, bk2 + l * Dn, bv2 + l * Dn,
            b1, b2, b3);
        k_attn_mfma<<<gA, blkA, 0, stream>>>(b1, b2, b3, b4);
        k_gemm2ph<128, false, true><<<gW, blk, 0, stream>>>(
            b4, wo2t + l * WSL, bo2 + l * Dn, x, x, BSn, Dn, Dn, 128, 4);
        k_ln<<<gL, blk, 0, stream>>>(x, g2 + l * Dn, be2 + l * Dn, x);
        // ---- feed-forward ----
        k_gemm8ph<true><<<g8, blk8, 0, stream>>>(
            x, w1ft + l * WFL, b1f + l * Fn, h1, BSn, Fn, Dn, 8);
        k_gemm2ph<128, false, true><<<gW, blk, 0, stream>>>(
            h1, w2ft + l * WFL, b2f + l * Dn, x, x, BSn, Dn, Fn, 128, 4);
        k_ln<<<gL, blk, 0, stream>>>(x, gfp + l * Dn, bff + l * Dn, x);
    }

    k_final2<<<dim3(BSn / 64), blk, 0, stream>>>(x, wcat, bcat, timei, out);
}

// Round 11
// 1245.613 us; speedup vs baseline: 1.0394x; 1.0394x over previous
//
#include <hip/hip_runtime.h>
#include <hip/hip_bf16.h>
#include <math.h>

// Problem constants
constexpr int Bn   = 32;
constexpr int Sn   = 256;
constexpr int Dn   = 512;
constexpr int Hn   = 8;
constexpr int DKn  = 64;
constexpr int Fn   = 2048;
constexpr int Ln   = 6;
constexpr int FEATn= 9;
constexpr int BSn  = Bn * Sn;          // 8192 rows

typedef __hip_bfloat16 bf16;
typedef __attribute__((ext_vector_type(8))) short short8;
typedef __attribute__((ext_vector_type(4))) short short4v;
typedef __attribute__((ext_vector_type(4))) float f32x4;

// global->LDS async copy, 16B per lane, LDS dest = wave-uniform base + lane*16
#define GLOAD_LDS16(gp, lp)                                                   \
    __builtin_amdgcn_global_load_lds(                                         \
        (const __attribute__((address_space(1))) void*)(gp),                  \
        (__attribute__((address_space(3))) void*)(lp), 16, 0, 0)

// raw barrier (NO implicit vmcnt drain) + compiler fences
#define BARRIER do {                                                          \
    __builtin_amdgcn_sched_barrier(0);                                        \
    asm volatile("" ::: "memory");                                            \
    __builtin_amdgcn_s_barrier();                                             \
    asm volatile("" ::: "memory");                                            \
    __builtin_amdgcn_sched_barrier(0);                                        \
} while (0)

#define VMCNT0 do {                                                           \
    asm volatile("s_waitcnt vmcnt(0)" ::: "memory");                          \
    __builtin_amdgcn_sched_barrier(0);                                        \
} while (0)

#define LGKM0 do {                                                            \
    asm volatile("s_waitcnt lgkmcnt(0)" ::: "memory");                        \
    __builtin_amdgcn_sched_barrier(0);                                        \
} while (0)

__device__ __forceinline__ short f2bs(float f) {
    __hip_bfloat16 h = __float2bfloat16(f);
    return *reinterpret_cast<short*>(&h);
}
__device__ __forceinline__ float bs2f(short s) {
    unsigned u = ((unsigned)(unsigned short)s) << 16;
    return *reinterpret_cast<float*>(&u);
}

// ---------------------------------------------------------------------------
// Embedding: x = (tgt*mask)@w_f2h + b_f2h + pos_emb + emb_time/gender/race
// ---------------------------------------------------------------------------
__global__ __launch_bounds__(256)
void k_embed(const float* __restrict__ tgt, const float* __restrict__ mask,
             const float* __restrict__ w_f2h, const float* __restrict__ b_f2h,
             const int* __restrict__ timei, const int* __restrict__ gender,
             const int* __restrict__ race,
             const float* __restrict__ emb_t, const float* __restrict__ emb_g,
             const float* __restrict__ emb_r, bf16* __restrict__ x)
{
    int idx = blockIdx.x * 256 + threadIdx.x;   // over BSn*Dn
    int d  = idx & (Dn - 1);
    int bs = idx >> 9;                           // /Dn
    int b  = bs / Sn;
    int s  = bs & (Sn - 1);
    const float* tg = tgt  + (size_t)bs * FEATn;
    const float* mk = mask + (size_t)bs * FEATn;
    float acc = b_f2h[d];
    #pragma unroll
    for (int f = 0; f < FEATn; ++f) acc += tg[f] * mk[f] * w_f2h[f * Dn + d];
    float phase = (float)s * expf(-((float)d / (float)Dn) * 9.210340372f); // ln(1e4)
    acc += (d & 1) ? cosf(phase) : sinf(phase);
    acc += emb_t[(size_t)timei[bs] * Dn + d];
    acc += emb_g[(size_t)gender[b] * Dn + d];
    acc += emb_r[(size_t)race[b]   * Dn + d];
    x[idx] = __float2bfloat16(acc);
}

// ---------------------------------------------------------------------------
// fp32 -> bf16 elementwise convert
// ---------------------------------------------------------------------------
__global__ __launch_bounds__(256)
void k_cvt(const float* __restrict__ in, bf16* __restrict__ out)
{
    int i = blockIdx.x * 256 + threadIdx.x;
    out[i] = __float2bfloat16(in[i]);
}

// ---------------------------------------------------------------------------
// Transpose + convert: in fp32 [B][R][C] -> out bf16 [B][C][R]
// Batched over up to 6 source/dest pairs: z in [0, 6*ZB); sel = z / ZB.
// ---------------------------------------------------------------------------
__global__ __launch_bounds__(256)
void k_tcvt6(const float* __restrict__ i0, bf16* __restrict__ o0,
             const float* __restrict__ i1, bf16* __restrict__ o1,
             const float* __restrict__ i2, bf16* __restrict__ o2,
             const float* __restrict__ i3, bf16* __restrict__ o3,
             const float* __restrict__ i4, bf16* __restrict__ o4,
             const float* __restrict__ i5, bf16* __restrict__ o5,
             int R, int C, int ZB)
{
    __shared__ float ts[32][33];
    const int sel = blockIdx.z / ZB, zi = blockIdx.z % ZB;
    const float* in  = sel == 0 ? i0 : sel == 1 ? i1 : sel == 2 ? i2
                     : sel == 3 ? i3 : sel == 4 ? i4 : i5;
    bf16*        out = sel == 0 ? o0 : sel == 1 ? o1 : sel == 2 ? o2
                     : sel == 3 ? o3 : sel == 4 ? o4 : o5;
    const int t  = threadIdx.x;
    const int tx = t & 31, ty = t >> 5;       // 8 rows per pass
    const int r0 = blockIdx.y * 32, c0 = blockIdx.x * 32;
    const size_t zo = (size_t)zi * R * C;
    #pragma unroll
    for (int i = 0; i < 4; ++i)
        ts[ty + 8 * i][tx] = in[zo + (size_t)(r0 + ty + 8 * i) * C + c0 + tx];
    __syncthreads();
    #pragma unroll
    for (int i = 0; i < 4; ++i)
        out[zo + (size_t)(c0 + ty + 8 * i) * R + r0 + tx] =
            __float2bfloat16(ts[tx][ty + 8 * i]);
}

// ---------------------------------------------------------------------------
// Prep for k_final2: Wcat bf16 [32][512] = concat(w_out^T, w_m^T, zero-pad),
// bcat fp32 [32] = concat(b_out, b_m, 0)
// ---------------------------------------------------------------------------
__global__ __launch_bounds__(256)
void k_prep_final(const float* __restrict__ w_out, const float* __restrict__ b_out,
                  const float* __restrict__ w_m, const float* __restrict__ b_m,
                  bf16* __restrict__ Wcat, float* __restrict__ bcat)
{
    int idx = blockIdx.x * 256 + threadIdx.x;   // 32*512
    int n = idx >> 9, k = idx & 511;
    float v = 0.f;
    if (n < FEATn)          v = w_out[(size_t)k * FEATn + n];
    else if (n < 2 * FEATn) v = w_m[(size_t)k * FEATn + (n - FEATn)];
    Wcat[idx] = __float2bfloat16(v);
    if (idx < 32) {
        float bv = idx < FEATn ? b_out[idx]
                 : (idx < 2 * FEATn ? b_m[idx - FEATn] : 0.f);
        bcat[idx] = bv;
    }
}

// ---------------------------------------------------------------------------
// 64xBN double-buffered prefetch 2-phase GEMM:
//   C[M,N] = (relu)(A[M,K] @ W[N,K]^T + bias) (+R residual)
// BK=64, 256 thr = 4 waves 2x2 (per-wave 32 x BN/2).  Per K-tile: {ds_read
// cur-buf frags || issue stage(next) into other buf -> lgkmcnt(0) -> MFMA ->
// vmcnt(0)+barrier}.  T2 chunk-XOR swizzle via pre-swizzled global source +
// swizzled ds_read.  Used for wo and ffn2.
// ---------------------------------------------------------------------------
template<int BN, bool RELU, bool RESID>
__global__ __launch_bounds__(256)
void k_gemm2ph(const bf16* __restrict__ Ain, const bf16* __restrict__ Win,
               const float* __restrict__ bia, const bf16* __restrict__ Rr,
               bf16* __restrict__ Cout, int M, int N, int K, int MTt, int NTt)
{
    constexpr int NT   = BN / 32;          // B frags per wave
    constexpr int NCB  = BN / 32;          // B staging calls (32 rows each)
    constexpr int BSZ  = BN * 64;          // B tile shorts
    constexpr int CSTR = BN + 8;           // epilogue row stride (shorts)
    constexpr int CPR  = BN / 8;           // 16B chunks per epilogue row
    __shared__ __align__(16) short smem[8192 + 2 * BSZ];

    // XCD swizzle: id&7 owns contiguous m-range (A-stationary)
    const int id = blockIdx.x;
    const int cx = id & 7, j = id >> 3;
    const int mt = cx * (MTt >> 3) + j / NTt;
    const int nt = j % NTt;
    const int m0 = mt * 64, n0 = nt * BN;

    const int t = threadIdx.x, w = t >> 6, lane = t & 63;
    const int l16 = lane & 15, quad = lane >> 4;
    const int wm = (w & 1) * 32, wn = (w >> 1) * (BN / 2);

    const short* A = (const short*)Ain;
    const short* W = (const short*)Win;

    // staging: 256 thr x 16B = 32 rows/call
    const int rowL = t >> 3;                     // 0..31
    const int cX   = (t & 7) ^ (rowL & 7);       // pre-swizzled k-chunk
    const short* pA0 = A + (size_t)(m0 +  0 + rowL) * K + cX * 8;
    const short* pA1 = A + (size_t)(m0 + 32 + rowL) * K + cX * 8;
    const short* pB[NCB];
    #pragma unroll
    for (int i = 0; i < NCB; ++i)
        pB[i] = W + (size_t)(n0 + i * 32 + rowL) * K + cX * 8;

    auto stage = [&](int nb, int k2) {
        short* dA = smem + nb * 4096 + t * 8;
        short* dB = smem + 8192 + nb * BSZ + t * 8;
        GLOAD_LDS16(pA0 + (size_t)k2 * 64, dA);
        GLOAD_LDS16(pA1 + (size_t)k2 * 64, dA + 2048);
        #pragma unroll
        for (int i = 0; i < NCB; ++i)
            GLOAD_LDS16(pB[i] + (size_t)k2 * 64, dB + i * 2048);
    };

    // fragment read bases (swizzled): addr = row*64 + ((chunk ^ (row&7))<<3)
    const int axor  = (quad ^ (l16 & 7)) << 3;
    const int aBase = (wm + l16) * 64 + axor;
    const int bBase = 8192 + (wn + l16) * 64 + axor;

    float bias_v[NT];
    #pragma unroll
    for (int ni = 0; ni < NT; ++ni)
        bias_v[ni] = bia[n0 + wn + ni * 16 + l16];

    f32x4 acc[2][NT] = {};

    stage(0, 0);
    VMCNT0;
    BARRIER;

    const int NKT = K >> 6;
    for (int kt = 0; kt < NKT; ++kt) {
        const int bufA = (kt & 1) * 4096;
        const int bufB = (kt & 1) * BSZ;
        short8 af[2][2], bw[2][NT];              // [ks][frag]
        #pragma unroll
        for (int mi = 0; mi < 2; ++mi) {
            const int a0 = bufA + aBase + mi * 1024;
            af[0][mi] = *(const short8*)(smem + a0);
            af[1][mi] = *(const short8*)(smem + (a0 ^ 32));  // ks=1: chunk^=4
        }
        #pragma unroll
        for (int ni = 0; ni < NT; ++ni) {
            const int b0 = bufB + bBase + ni * 1024;
            bw[0][ni] = *(const short8*)(smem + b0);
            bw[1][ni] = *(const short8*)(smem + (b0 ^ 32));
        }
        if (kt + 1 < NKT) stage((kt + 1) & 1, kt + 1);
        LGKM0;
        __builtin_amdgcn_s_setprio(1);
        #pragma unroll
        for (int ks = 0; ks < 2; ++ks)
            #pragma unroll
            for (int mi = 0; mi < 2; ++mi)
                #pragma unroll
                for (int ni = 0; ni < NT; ++ni)
                    acc[mi][ni] = __builtin_amdgcn_mfma_f32_16x16x32_bf16(
                        af[ks][mi], bw[ks][ni], acc[mi][ni], 0, 0, 0);
        __builtin_amdgcn_s_setprio(0);
        VMCNT0;
        BARRIER;
    }

    // epilogue: stage [64][CSTR] in smem, coalesced b128 stores
    #pragma unroll
    for (int mi = 0; mi < 2; ++mi)
        #pragma unroll
        for (int ni = 0; ni < NT; ++ni)
            #pragma unroll
            for (int r = 0; r < 4; ++r) {
                float v = acc[mi][ni][r] + bias_v[ni];
                if (RELU) v = fmaxf(v, 0.f);
                smem[(wm + mi * 16 + quad * 4 + r) * CSTR
                     + wn + ni * 16 + l16] = f2bs(v);
            }
    LGKM0;
    BARRIER;
    #pragma unroll
    for (int cc = 0; cc < 64 * CPR; cc += 256) {
        const int idx = cc + t;
        const int row = idx / CPR, colc = idx % CPR;
        const size_t goff = (size_t)(m0 + row) * N + n0 + colc * 8;
        short8 cv = *(const short8*)(smem + row * CSTR + colc * 8);
        if (RESID) {
            short8 rv = *(const short8*)((const short*)Rr + goff);
            short8 ov;
            #pragma unroll
            for (int i = 0; i < 8; ++i)
                ov[i] = f2bs(bs2f(cv[i]) + bs2f(rv[i]));
            *(short8*)((short*)Cout + goff) = ov;
        } else {
            *(short8*)((short*)Cout + goff) = cv;
        }
    }
}

// ---------------------------------------------------------------------------
// 8-phase helpers with REGISTER-CACHED fragments (sync structure identical to
// the verified 4x gemm8_phase schedule; redundant ds_reads eliminated --
// 24 b128 reads per wave per K-tile instead of 48; LDS-read bound at K=512).
// ---------------------------------------------------------------------------
__device__ __forceinline__ void read_afrag(const short* sm, int base,
                                           short8 (&pa)[2][4])
{
    #pragma unroll
    for (int i = 0; i < 4; ++i) {
        const int a0 = base + i * 1024;
        pa[0][i] = *(const short8*)(sm + a0);
        pa[1][i] = *(const short8*)(sm + (a0 ^ 32));   // ks=1: chunk ^= 4
    }
}
__device__ __forceinline__ void read_bfrag(const short* sm, int base,
                                           short8 (&pb)[2][2])
{
    #pragma unroll
    for (int j = 0; j < 2; ++j) {
        const int b0 = base + j * 1024;
        pb[0][j] = *(const short8*)(sm + b0);
        pb[1][j] = *(const short8*)(sm + (b0 ^ 32));
    }
}
template<int RH, int CH>
__device__ __forceinline__ void mfma_quad(short8 (&pa)[2][4], short8 (&pb)[2][2],
                                          f32x4 (&acc)[8][4])
{
    #pragma unroll
    for (int i = 0; i < 4; ++i)
        #pragma unroll
        for (int j = 0; j < 2; ++j) {
            acc[RH * 4 + i][CH * 2 + j] = __builtin_amdgcn_mfma_f32_16x16x32_bf16(
                pa[0][i], pb[0][j], acc[RH * 4 + i][CH * 2 + j], 0, 0, 0);
            acc[RH * 4 + i][CH * 2 + j] = __builtin_amdgcn_mfma_f32_16x16x32_bf16(
                pa[1][i], pb[1][j], acc[RH * 4 + i][CH * 2 + j], 0, 0, 0);
        }
}

// One full K-tile = 4 phases with the SAME barrier/stage/fin placement as the
// original {(0,0)stgA, (0,1)stgB, (1,0), (1,1)fin} sequence; A0/B0/A1/B1 are
// read once each and carried in registers across phases (buf is not written
// during this K-tile -- staging targets the other buffer).
template<class STGA, class STGB, class FIN>
__device__ __forceinline__ void gemm8_kt(short* sm, int buf, int baseA,
                                         int baseB, f32x4 (&acc)[8][4],
                                         STGA stgA, STGB stgB, FIN fin)
{
    short8 pa0[2][4], pa1[2][4], pb0[2][2], pb1[2][2];
    // phase (0,0): read A-half0 + B-half0, issue A staging
    read_afrag(sm, buf + baseA, pa0);
    read_bfrag(sm, buf + baseB, pb0);
    stgA();
    BARRIER;
    __builtin_amdgcn_s_setprio(1);
    mfma_quad<0, 0>(pa0, pb0, acc);
    __builtin_amdgcn_s_setprio(0);
    BARRIER;
    // phase (0,1): read B-half1 only (A0 cached), issue B staging
    read_bfrag(sm, buf + baseB + 2048, pb1);
    stgB();
    BARRIER;
    __builtin_amdgcn_s_setprio(1);
    mfma_quad<0, 1>(pa0, pb1, acc);
    __builtin_amdgcn_s_setprio(0);
    BARRIER;
    // phase (1,0): read A-half1 only (B0 cached)
    read_afrag(sm, buf + baseA + 4096, pa1);
    BARRIER;
    __builtin_amdgcn_s_setprio(1);
    mfma_quad<1, 0>(pa1, pb0, acc);
    __builtin_amdgcn_s_setprio(0);
    BARRIER;
    // phase (1,1): no reads (A1,B1 cached)
    BARRIER;
    __builtin_amdgcn_s_setprio(1);
    mfma_quad<1, 1>(pa1, pb1, acc);
    __builtin_amdgcn_s_setprio(0);
    fin();
    BARRIER;
}

// ---------------------------------------------------------------------------
// 256x256 8-phase bf16 GEMM (T2 swizzle + T3/T4 counted-wait phases + T5
// setprio).  C[M,N] = relu(A[M,K] @ W[N,K]^T + bias).  512 thr = 8 waves
// (2M x 4N), per-wave 128x64, BK=64, LDS 128 KiB dbuf.  Used for ffn1.
// ---------------------------------------------------------------------------
template<bool RELU>
__global__ __launch_bounds__(512, 2)
void k_gemm8ph(const bf16* __restrict__ Ain, const bf16* __restrict__ Win,
               const float* __restrict__ bia, bf16* __restrict__ Cout,
               int M, int N, int K, int NTt)
{
    __shared__ __align__(16) short smem[65536];   // 128 KiB: A 64K | B 64K

    // ---- XCD swizzle decode (A-stationary: id&7 owns contiguous m-range) --
    const int id  = blockIdx.x;
    const int cxd = id & 7, jj = id >> 3;
    const int mpx = (M >> 8) >> 3;                // (M/256)/8
    const int ml  = jj / NTt, nl = jj % NTt;
    const int mt  = cxd * mpx + ml;
    const int m0  = mt * 256, n0 = nl * 256;

    const int t    = threadIdx.x;
    const int lane = t & 63, w = t >> 6;
    const int l16  = lane & 15, quad = lane >> 4;
    const int wr   = w >> 2, wc = w & 3;          // wave grid 2M x 4N

    const short* A = (const short*)Ain;
    const short* W = (const short*)Win;

    // ---- staging geometry (per-thread, both halves x both passes) --------
    const int rowL = t >> 3;                      // 0..63
    const int cX   = (t & 7) ^ (rowL & 7);        // pre-swizzled k-chunk
    const short* pA00 = A + (size_t)(m0 +   0 +  0 + rowL) * K + cX * 8;
    const short* pA01 = A + (size_t)(m0 +   0 + 64 + rowL) * K + cX * 8;
    const short* pA10 = A + (size_t)(m0 + 128 +  0 + rowL) * K + cX * 8;
    const short* pA11 = A + (size_t)(m0 + 128 + 64 + rowL) * K + cX * 8;
    const short* pB00 = W + (size_t)(n0 +   0 +  0 + rowL) * K + cX * 8;
    const short* pB01 = W + (size_t)(n0 +   0 + 64 + rowL) * K + cX * 8;
    const short* pB10 = W + (size_t)(n0 + 128 +  0 + rowL) * K + cX * 8;
    const short* pB11 = W + (size_t)(n0 + 128 + 64 + rowL) * K + cX * 8;

    auto stageA = [&](int nb, int k2) {
        short* d = smem + nb * 16384 + t * 8;
        GLOAD_LDS16(pA00 + (size_t)k2 * 64, d);
        GLOAD_LDS16(pA01 + (size_t)k2 * 64, d + 4096);
        GLOAD_LDS16(pA10 + (size_t)k2 * 64, d + 8192);
        GLOAD_LDS16(pA11 + (size_t)k2 * 64, d + 12288);
    };
    auto stageB = [&](int nb, int k2) {
        short* d = smem + 32768 + nb * 16384 + t * 8;
        GLOAD_LDS16(pB00 + (size_t)k2 * 64, d);
        GLOAD_LDS16(pB01 + (size_t)k2 * 64, d + 4096);
        GLOAD_LDS16(pB10 + (size_t)k2 * 64, d + 8192);
        GLOAD_LDS16(pB11 + (size_t)k2 * 64, d + 12288);
    };

    // ---- fragment read bases (swizzled; A-half = wr, B-half = wc>>1) -----
    const int axor  = (quad ^ (l16 & 7)) << 3;
    const int baseA = wr * 8192 + l16 * 64 + axor;
    const int baseB = 32768 + (wc >> 1) * 8192 + (wc & 1) * 4096
                    + l16 * 64 + axor;

    float bias_v[4];
    #pragma unroll
    for (int ni = 0; ni < 4; ++ni)
        bias_v[ni] = bia[n0 + wc * 64 + ni * 16 + l16];

    f32x4 acc[8][4] = {};

    // ---- prologue: stage tile 0 fully ------------------------------------
    stageA(0, 0);
    stageB(0, 0);
    VMCNT0;
    BARRIER;

    const int NKT = K >> 6;
    for (int kt = 0; kt < NKT; ++kt) {
        const int  buf = (kt & 1) << 14;          // *16384 shorts
        const int  nb  = (kt + 1) & 1;
        const bool st  = (kt + 1) < NKT;
        gemm8_kt(smem, buf, baseA, baseB, acc,
                 [&] { if (st) stageA(nb, kt + 1); },
                 [&] { if (st) stageB(nb, kt + 1); },
                 [&] { VMCNT0; });
    }

    // ---- epilogue: 2 row-half passes through LDS, coalesced b128 stores --
    #pragma unroll
    for (int p = 0; p < 2; ++p) {
        if (wr == p) {
            #pragma unroll
            for (int mi = 0; mi < 8; ++mi)
                #pragma unroll
                for (int ni = 0; ni < 4; ++ni)
                    #pragma unroll
                    for (int r = 0; r < 4; ++r) {
                        float v = acc[mi][ni][r] + bias_v[ni];
                        if (RELU) v = fmaxf(v, 0.f);
                        smem[(mi * 16 + quad * 4 + r) * 264
                             + wc * 64 + ni * 16 + l16] = f2bs(v);
                    }
        }
        LGKM0;
        BARRIER;
        #pragma unroll
        for (int i2 = 0; i2 < 8; ++i2) {
            const int idx = i2 * 512 + t;
            const int row = idx >> 5, chn = idx & 31;
            short8 cv = *(const short8*)(smem + row * 264 + chn * 8);
            *(short8*)((short*)Cout + (size_t)(m0 + p * 128 + row) * N
                                     + n0 + chn * 8) = cv;
        }
        LGKM0;
        BARRIER;
    }
}

// ---------------------------------------------------------------------------
// Fused QKV projection as one 256x256 8-phase GEMM over virtual N = 1536.
// 32 m-tiles x 6 n-tiles = 192 wgs; sel = nl>>1 picks {q,k,v} weight/bias/
// output (and A operand: q,k from Aqk, v from Av -- differs for cross-attn).
// sel<2: standard epilogue into Cq/Ck [8192][512] at col (nl&1)*256.
// sel==2: TRANSPOSED epilogue into Vt [512][8192] (what k_attn_mfma needs),
// 4 passes of 64 n-rows staged [64][264] in LDS, coalesced 16B stores.
// ---------------------------------------------------------------------------
__global__ __launch_bounds__(512, 2)
void k_qkv8ph(const bf16* __restrict__ Aqk, const bf16* __restrict__ Av,
              const bf16* __restrict__ Wq, const bf16* __restrict__ Wk,
              const bf16* __restrict__ Wv,
              const float* __restrict__ bq, const float* __restrict__ bk,
              const float* __restrict__ bv,
              bf16* __restrict__ Cq, bf16* __restrict__ Ck,
              bf16* __restrict__ Vt)
{
    __shared__ __align__(16) short smem[65536];   // 128 KiB

    constexpr int K = Dn;                          // 512
    // ---- decode: cxd owns 4 contiguous m-tiles, iterates 6 n-tiles -------
    const int id  = blockIdx.x;                    // 0..191
    const int cxd = id & 7, jj = id >> 3;          // jj 0..23
    const int ml  = jj / 6, nl = jj % 6;
    const int mt  = cxd * 4 + ml;
    const int m0  = mt * 256;
    const int sel = nl >> 1;                       // 0=q 1=k 2=v
    const int n0l = (nl & 1) * 256;                // col offset in 512-wide out

    const short* A = (const short*)(sel < 2 ? Aqk : Av);
    const short* W = (const short*)(sel == 0 ? Wq : sel == 1 ? Wk : Wv);
    const float* bia = sel == 0 ? bq : sel == 1 ? bk : bv;

    const int t    = threadIdx.x;
    const int lane = t & 63, w = t >> 6;
    const int l16  = lane & 15, quad = lane >> 4;
    const int wr   = w >> 2, wc = w & 3;

    // ---- staging geometry ------------------------------------------------
    const int rowL = t >> 3;
    const int cX   = (t & 7) ^ (rowL & 7);
    const short* pA00 = A + (size_t)(m0 +   0 +  0 + rowL) * K + cX * 8;
    const short* pA01 = A + (size_t)(m0 +   0 + 64 + rowL) * K + cX * 8;
    const short* pA10 = A + (size_t)(m0 + 128 +  0 + rowL) * K + cX * 8;
    const short* pA11 = A + (size_t)(m0 + 128 + 64 + rowL) * K + cX * 8;
    const short* pB00 = W + (size_t)(n0l +   0 +  0 + rowL) * K + cX * 8;
    const short* pB01 = W + (size_t)(n0l +   0 + 64 + rowL) * K + cX * 8;
    const short* pB10 = W + (size_t)(n0l + 128 +  0 + rowL) * K + cX * 8;
    const short* pB11 = W + (size_t)(n0l + 128 + 64 + rowL) * K + cX * 8;

    auto stageA = [&](int nb, int k2) {
        short* d = smem + nb * 16384 + t * 8;
        GLOAD_LDS16(pA00 + (size_t)k2 * 64, d);
        GLOAD_LDS16(pA01 + (size_t)k2 * 64, d + 4096);
        GLOAD_LDS16(pA10 + (size_t)k2 * 64, d + 8192);
        GLOAD_LDS16(pA11 + (size_t)k2 * 64, d + 12288);
    };
    auto stageB = [&](int nb, int k2) {
        short* d = smem + 32768 + nb * 16384 + t * 8;
        GLOAD_LDS16(pB00 + (size_t)k2 * 64, d);
        GLOAD_LDS16(pB01 + (size_t)k2 * 64, d + 4096);
        GLOAD_LDS16(pB10 + (size_t)k2 * 64, d + 8192);
        GLOAD_LDS16(pB11 + (size_t)k2 * 64, d + 12288);
    };

    const int axor  = (quad ^ (l16 & 7)) << 3;
    const int baseA = wr * 8192 + l16 * 64 + axor;
    const int baseB = 32768 + (wc >> 1) * 8192 + (wc & 1) * 4096
                    + l16 * 64 + axor;

    float bias_v[4];
    #pragma unroll
    for (int ni = 0; ni < 4; ++ni)
        bias_v[ni] = bia[n0l + wc * 64 + ni * 16 + l16];

    f32x4 acc[8][4] = {};

    stageA(0, 0);
    stageB(0, 0);
    VMCNT0;
    BARRIER;

    constexpr int NKT = K >> 6;                   // 8
    for (int kt = 0; kt < NKT; ++kt) {
        const int  buf = (kt & 1) << 14;
        const int  nb  = (kt + 1) & 1;
        const bool st  = (kt + 1) < NKT;
        gemm8_kt(smem, buf, baseA, baseB, acc,
                 [&] { if (st) stageA(nb, kt + 1); },
                 [&] { if (st) stageB(nb, kt + 1); },
                 [&] { VMCNT0; });
    }

    if (sel < 2) {
        bf16* C = sel == 0 ? Cq : Ck;
        #pragma unroll
        for (int p = 0; p < 2; ++p) {
            if (wr == p) {
                #pragma unroll
                for (int mi = 0; mi < 8; ++mi)
                    #pragma unroll
                    for (int ni = 0; ni < 4; ++ni)
                        #pragma unroll
                        for (int r = 0; r < 4; ++r)
                            smem[(mi * 16 + quad * 4 + r) * 264
                                 + wc * 64 + ni * 16 + l16] =
                                f2bs(acc[mi][ni][r] + bias_v[ni]);
            }
            LGKM0;
            BARRIER;
            #pragma unroll
            for (int i2 = 0; i2 < 8; ++i2) {
                const int idx = i2 * 512 + t;
                const int row = idx >> 5, chn = idx & 31;
                short8 cv = *(const short8*)(smem + row * 264 + chn * 8);
                *(short8*)((short*)C + (size_t)(m0 + p * 128 + row) * Dn
                                     + n0l + chn * 8) = cv;
            }
            LGKM0;
            BARRIER;
        }
    } else {
        // transposed epilogue: Vt[n0l + n][m0 + m], 4 passes of 64 n-rows
        #pragma unroll
        for (int p = 0; p < 4; ++p) {
            if (wc == p) {
                #pragma unroll
                for (int mi = 0; mi < 8; ++mi)
                    #pragma unroll
                    for (int ni = 0; ni < 4; ++ni)
                        #pragma unroll
                        for (int r = 0; r < 4; ++r)
                            smem[(ni * 16 + l16) * 264
                                 + wr * 128 + mi * 16 + quad * 4 + r] =
                                f2bs(acc[mi][ni][r] + bias_v[ni]);
            }
            LGKM0;
            BARRIER;
            #pragma unroll
            for (int i2 = 0; i2 < 4; ++i2) {
                const int idx = i2 * 512 + t;
                const int row = idx >> 5, chn = idx & 31;   // row<64, chn<32
                short8 cv = *(const short8*)(smem + row * 264 + chn * 8);
                *(short8*)((short*)Vt + (size_t)(n0l + p * 64 + row) * BSn
                                      + m0 + chn * 8) = cv;
            }
            LGKM0;
            BARRIER;
        }
    }
}

// ---------------------------------------------------------------------------
// MFMA attention, stage-once per (b,h).  q,k in [B,S,H*DK]; vT in
// [H*DK][B*S]; out in [B,S,H*DK].  Block = (b,h): 1024 thr = 16 waves, each
// wave owns 16 q-rows.  Grid = 256 = exact 1 block/CU.  K (32KB) + V (32KB)
// staged ONCE; P in per-wave PRIVATE 16x128 LDS slices (64KB, chunk-XOR
// swizzled), two 128-key halves reuse the slice -> ONE __syncthreads().
// ---------------------------------------------------------------------------
__global__ __launch_bounds__(1024)
void k_attn_mfma(const bf16* __restrict__ q, const bf16* __restrict__ k,
                 const bf16* __restrict__ vT, bf16* __restrict__ ocat)
{
    __shared__ __align__(16) short smem[65536];   // 128 KiB
    short* Vst = smem;            // [64 dv][256 key], 16B chunks XOR-swizzled
    short* Ks  = smem + 16384;    // [256 key][64 dk], 16B chunks XOR-swizzled
    short* Ps  = smem + 32768;    // 16 x per-wave [16 q][128 k] slices

    const int t = threadIdx.x, w = t >> 6, lane = t & 63;
    const int l16 = lane & 15, quad = lane >> 4;
    const int bh = blockIdx.x;
    const int h  = bh & 7;
    const int b  = bh >> 3;

    const short* kg = (const short*)k  + (size_t)b * Sn * Dn + h * DKn;
    const short* qg = (const short*)q  + (size_t)b * Sn * Dn + h * DKn;
    const short* vg = (const short*)vT + (size_t)h * DKn * BSn + b * Sn;

    #pragma unroll
    for (int i = 0; i < 2; ++i) {
        const int c   = i * 1024 + w * 64 + lane;
        const int key = c >> 3, cgk = (c & 7) ^ (key & 7);
        GLOAD_LDS16(kg + (size_t)key * Dn + cgk * 8, Ks + (i * 1024 + w * 64) * 8);
        const int dv = c >> 5, cgv = (c & 31) ^ (dv & 7);
        GLOAD_LDS16(vg + (size_t)dv * BSn + cgv * 8, Vst + (i * 1024 + w * 64) * 8);
    }

    const short* qp = qg + (size_t)(w * 16 + l16) * Dn + quad * 8;
    short8 bq0 = *(const short8*)(qp);
    short8 bq1 = *(const short8*)(qp + 32);
    __syncthreads();    // drains vmcnt (K/V landed); the ONLY barrier

    // ---- S^T = K @ Q^T : per-lane 64 scores of q-row l16 ----
    f32x4 accs[16];
    #pragma unroll
    for (int mi = 0; mi < 16; ++mi) accs[mi] = f32x4{0.f, 0.f, 0.f, 0.f};
    #pragma unroll
    for (int mi = 0; mi < 16; ++mi) {
        const int key = mi * 16 + l16;
        const int r0s = (quad     ^ (key & 7)) * 8;
        const int r1s = ((quad+4) ^ (key & 7)) * 8;
        short8 af0 = *(const short8*)(Ks + key * 64 + r0s);
        short8 af1 = *(const short8*)(Ks + key * 64 + r1s);
        accs[mi] = __builtin_amdgcn_mfma_f32_16x16x32_bf16(af0, bq0, accs[mi], 0, 0, 0);
        accs[mi] = __builtin_amdgcn_mfma_f32_16x16x32_bf16(af1, bq1, accs[mi], 0, 0, 0);
    }

    // ---- softmax over keys (reduce across quad groups) ----
    float mx = -1e30f;
    #pragma unroll
    for (int mi = 0; mi < 16; ++mi)
        #pragma unroll
        for (int r = 0; r < 4; ++r) mx = fmaxf(mx, accs[mi][r]);
    mx = fmaxf(mx, __shfl_xor(mx, 16));
    mx = fmaxf(mx, __shfl_xor(mx, 32));
    float sum = 0.f;
    #pragma unroll
    for (int mi = 0; mi < 16; ++mi)
        #pragma unroll
        for (int r = 0; r < 4; ++r) {
            float e = __expf((accs[mi][r] - mx) * 0.125f);
            accs[mi][r] = e;
            sum += e;
        }
    sum += __shfl_xor(sum, 16);
    sum += __shfl_xor(sum, 32);
    const float rs = 1.f / sum;

    // ---- P -> private LDS slice, PV in two 128-key halves ----
    short* pr = Ps + w * 2048 + l16 * 128;        // this wave, this q-row
    const int psw = (l16 & 7) << 3;               // chunk-XOR swizzle

    f32x4 acco[4];
    #pragma unroll
    for (int nt = 0; nt < 4; ++nt) acco[nt] = f32x4{0.f, 0.f, 0.f, 0.f};

    #pragma unroll
    for (int half = 0; half < 2; ++half) {
        if (half) LGKM0;                          // slice reads done before reuse
        #pragma unroll
        for (int mi = 0; mi < 8; ++mi) {
            const int mg = half * 8 + mi;
            short4v pk;
            pk.x = f2bs(accs[mg][0] * rs);
            pk.y = f2bs(accs[mg][1] * rs);
            pk.z = f2bs(accs[mg][2] * rs);
            pk.w = f2bs(accs[mg][3] * rs);
            *(short4v*)(pr + ((mi * 16 + quad * 4) ^ psw)) = pk;
        }
        LGKM0;                                    // writes visible to own reads
        #pragma unroll
        for (int k0 = 0; k0 < 4; ++k0) {
            short8 pa = *(const short8*)(pr + ((k0 * 32 + quad * 8) ^ psw));
            #pragma unroll
            for (int nt = 0; nt < 4; ++nt) {
                const int dv = nt * 16 + l16;
                const int ch = 4 * (half * 4 + k0) + quad;
                const int sl = (ch ^ (dv & 7)) * 8;
                short8 vb = *(const short8*)(Vst + dv * 256 + sl);
                acco[nt] = __builtin_amdgcn_mfma_f32_16x16x32_bf16(
                    pa, vb, acco[nt], 0, 0, 0);
            }
        }
    }

    // ---- epilogue: reuse own slice as [16 q][72] staging, b128 stores ----
    LGKM0;                                        // PV reads done before overlay
    short* cs = Ps + w * 2048;
    #pragma unroll
    for (int nt = 0; nt < 4; ++nt)
        #pragma unroll
        for (int r = 0; r < 4; ++r)
            cs[(quad * 4 + r) * 72 + nt * 16 + l16] = f2bs(acco[nt][r]);
    LGKM0;
    #pragma unroll
    for (int j = 0; j < 2; ++j) {
        const int idx = j * 64 + lane;
        const int row = idx >> 3, colc = idx & 7;
        short8 cv = *(const short8*)(cs + row * 72 + colc * 8);
        *(short8*)((short*)ocat + (size_t)(b * Sn + w * 16 + row) * Dn
                                 + h * DKn + colc * 8) = cv;
    }
}

// ---------------------------------------------------------------------------
// LayerNorm over D=512: one wave per row, b128 loads, shfl-only reduction.
// ---------------------------------------------------------------------------
__global__ __launch_bounds__(256)
void k_ln(const bf16* __restrict__ y, const float* __restrict__ g,
          const float* __restrict__ be, bf16* __restrict__ xo)
{
    const int t = threadIdx.x, w = t >> 6, lane = t & 63;
    const int row = blockIdx.x * 4 + w;
    const short* yr = (const short*)y + (size_t)row * Dn + lane * 8;
    short8 v8 = *(const short8*)yr;
    float f[8];
    float s1 = 0.f, s2 = 0.f;
    #pragma unroll
    for (int i = 0; i < 8; ++i) {
        f[i] = bs2f(v8[i]);
        s1 += f[i];
        s2 += f[i] * f[i];
    }
    #pragma unroll
    for (int off = 1; off < 64; off <<= 1) {
        s1 += __shfl_xor(s1, off);
        s2 += __shfl_xor(s2, off);
    }
    const float mean = s1 * (1.f / Dn);
    const float var  = s2 * (1.f / Dn) - mean * mean;
    const float isd  = rsqrtf(var + 1e-5f);
    const float4 g0 = *(const float4*)(g  + lane * 8);
    const float4 g1 = *(const float4*)(g  + lane * 8 + 4);
    const float4 b0 = *(const float4*)(be + lane * 8);
    const float4 b1 = *(const float4*)(be + lane * 8 + 4);
    const float gg[8] = {g0.x, g0.y, g0.z, g0.w, g1.x, g1.y, g1.z, g1.w};
    const float bb[8] = {b0.x, b0.y, b0.z, b0.w, b1.x, b1.y, b1.z, b1.w};
    short8 o8;
    #pragma unroll
    for (int i = 0; i < 8; ++i)
        o8[i] = f2bs((f[i] - mean) * isd * gg[i] + bb[i]);
    *(short8*)((short*)xo + (size_t)row * Dn + lane * 8) = o8;
}

// ---------------------------------------------------------------------------
// Final head as skinny MFMA GEMM: out = sigmoid(X @ Wcat^T + bcat).
// ---------------------------------------------------------------------------
__global__ __launch_bounds__(256)
void k_final2(const bf16* __restrict__ x, const bf16* __restrict__ Wcat,
              const float* __restrict__ bcat, const int* __restrict__ timei,
              float* __restrict__ out)
{
    const int t = threadIdx.x, w = t >> 6, lane = t & 63;
    const int l16 = lane & 15, quad = lane >> 4;
    const int r0 = blockIdx.x * 64 + w * 16;
    const short* xp = (const short*)x + (size_t)(r0 + l16) * Dn + quad * 8;
    const short* wp = (const short*)Wcat + (size_t)l16 * Dn + quad * 8;

    f32x4 acc[2] = {};
    #pragma unroll
    for (int kk = 0; kk < 16; ++kk) {
        short8 af = *(const short8*)(xp + kk * 32);
        short8 b0 = *(const short8*)(wp + kk * 32);
        short8 b1 = *(const short8*)(wp + 16 * Dn + kk * 32);
        acc[0] = __builtin_amdgcn_mfma_f32_16x16x32_bf16(af, b0, acc[0], 0, 0, 0);
        acc[1] = __builtin_amdgcn_mfma_f32_16x16x32_bf16(af, b1, acc[1], 0, 0, 0);
    }

    #pragma unroll
    for (int nt = 0; nt < 2; ++nt) {
        const int col = nt * 16 + l16;
        const float bb = bcat[col];
        #pragma unroll
        for (int r = 0; r < 4; ++r) {
            const int row = r0 + quad * 4 + r;
            float v = acc[nt][r] + bb;
            float sg = 1.f / (1.f + expf(-v));
            if (col < FEATn)
                out[(size_t)row * FEATn + col] = sg;
            else if (col < 2 * FEATn)
                out[(size_t)BSn * FEATn + BSn + (size_t)row * FEATn + (col - FEATn)] = sg;
        }
    }
    if (l16 == 0) {
        #pragma unroll
        for (int r = 0; r < 4; ++r) {
            const int row = r0 + quad * 4 + r;
            out[(size_t)BSn * FEATn + row] = (float)timei[row];
        }
    }
}

// ---------------------------------------------------------------------------
extern "C" void kernel_launch(void* const* d_in, const int* in_sizes, int n_in,
                              void* d_out, int out_size, void* d_ws, size_t ws_size,
                              hipStream_t stream)
{
    const float* tgt    = (const float*)d_in[0];
    const float* memory = (const float*)d_in[1];
    const int*   timei  = (const int*)  d_in[2];
    const int*   gender = (const int*)  d_in[3];
    const int*   race   = (const int*)  d_in[4];
    const float* maskp  = (const float*)d_in[5];
    const float* w_f2h  = (const float*)d_in[6];
    const float* b_f2h  = (const float*)d_in[7];
    const float* emb_t  = (const float*)d_in[8];
    const float* emb_g  = (const float*)d_in[9];
    const float* emb_r  = (const float*)d_in[10];
    const float* wq1 = (const float*)d_in[11]; const float* bq1 = (const float*)d_in[12];
    const float* wk1 = (const float*)d_in[13]; const float* bk1 = (const float*)d_in[14];
    const float* wv1 = (const float*)d_in[15]; const float* bv1 = (const float*)d_in[16];
    const float* wo1 = (const float*)d_in[17]; const float* bo1 = (const float*)d_in[18];
    const float* g1  = (const float*)d_in[19]; const float* be1 = (const float*)d_in[20];
    const float* wq2 = (const float*)d_in[21]; const float* bq2 = (const float*)d_in[22];
    const float* wk2 = (const float*)d_in[23]; const float* bk2 = (const float*)d_in[24];
    const float* wv2 = (const float*)d_in[25]; const float* bv2 = (const float*)d_in[26];
    const float* wo2 = (const float*)d_in[27]; const float* bo2 = (const float*)d_in[28];
    const float* g2  = (const float*)d_in[29]; const float* be2 = (const float*)d_in[30];
    const float* w1f = (const float*)d_in[31]; const float* b1f = (const float*)d_in[32];
    const float* w2f = (const float*)d_in[33]; const float* b2f = (const float*)d_in[34];
    const float* gfp = (const float*)d_in[35]; const float* bff = (const float*)d_in[36];
    const float* w_out = (const float*)d_in[37]; const float* b_out = (const float*)d_in[38];
    const float* w_m   = (const float*)d_in[39]; const float* b_m   = (const float*)d_in[40];
    float* out = (float*)d_out;

    // ---- workspace layout (bf16 elems) ----
    constexpr size_t WH  = 1572864;            // headed / wo per-array
    constexpr size_t WF  = 6291456;            // w1f / w2f per-array
    constexpr size_t NA  = (size_t)BSn * Dn;   // activation elems
    bf16* wsb   = (bf16*)d_ws;
    bf16* wq1t  = wsb;
    bf16* wk1t  = wq1t + WH;
    bf16* wv1t  = wk1t + WH;
    bf16* wo1t  = wv1t + WH;
    bf16* wq2t  = wo1t + WH;
    bf16* wk2t  = wq2t + WH;
    bf16* wv2t  = wk2t + WH;
    bf16* wo2t  = wv2t + WH;
    bf16* w1ft  = wo2t + WH;
    bf16* w2ft  = w1ft + WF;
    bf16* memb  = w2ft + WF;
    bf16* x     = memb + NA;
    bf16* b1    = x  + NA;
    bf16* b2    = b1 + NA;
    bf16* b3    = b2 + NA;     // Vt [512][8192] from v-proj transposed epilogue
    bf16* b4    = b3 + NA;
    bf16* h1    = b1;          // [8192][2048] spans b1..b4
    bf16* wcat  = b4 + NA;     // [32][512]
    float* bcat = (float*)(wcat + 32 * Dn);

    dim3 blk(256);

    // ---- weight transpose+convert (batched) ----
    k_tcvt6<<<dim3( 2, 16, 288), blk, 0, stream>>>(
        wq1, wq1t, wk1, wk1t, wv1, wv1t, wq2, wq2t, wk2, wk2t, wv2, wv2t,
        512, 64, 48);
    k_tcvt6<<<dim3(16, 16, 12), blk, 0, stream>>>(
        wo1, wo1t, wo2, wo2t, wo1, wo1t, wo1, wo1t, wo1, wo1t, wo1, wo1t,
        512, 512, 6);
    k_tcvt6<<<dim3(64, 16, 6), blk, 0, stream>>>(
        w1f, w1ft, w1f, w1ft, w1f, w1ft, w1f, w1ft, w1f, w1ft, w1f, w1ft,
        512, 2048, 6);
    k_tcvt6<<<dim3(16, 64, 6), blk, 0, stream>>>(
        w2f, w2ft, w2f, w2ft, w2f, w2ft, w2f, w2ft, w2f, w2ft, w2f, w2ft,
        2048, 512, 6);
    k_cvt <<<dim3(NA / 256), blk, 0, stream>>>(memory, memb);
    k_prep_final<<<dim3(64), blk, 0, stream>>>(w_out, b_out, w_m, b_m, wcat, bcat);

    k_embed<<<dim3((BSn * Dn) / 256), blk, 0, stream>>>(
        tgt, maskp, w_f2h, b_f2h, timei, gender, race, emb_t, emb_g, emb_r, x);

    // grids
    dim3 gQ (192);            // qkv 8-phase: 32 m-tiles x 6 n-tiles
    dim3 gW (128 * 4);        // wo / ffn2 2-phase 64x128: MT=128, NT=4
    dim3 g8 (32 * 8);         // ffn1 8-phase 256x256: (M/256)*(N/256) = 256 wgs
    dim3 blk8(512);
    dim3 gA (Bn * Hn);        // attn: one 1024-thr block per (b,h), 1/CU
    dim3 blkA(1024);
    dim3 gL (BSn / 4);
    constexpr size_t WSL = 262144;
    constexpr size_t WFL = 1048576;

    for (int l = 0; l < Ln; ++l) {
        // ---- self-attention ----
        k_qkv8ph<<<gQ, blk8, 0, stream>>>(
            x, x,
            wq1t + l * WSL, wk1t + l * WSL, wv1t + l * WSL,
            bq1 + l * Dn, bk1 + l * Dn, bv1 + l * Dn,
            b1, b2, b3);
        k_attn_mfma<<<gA, blkA, 0, stream>>>(b1, b2, b3, b4);
        k_gemm2ph<128, false, true><<<gW, blk, 0, stream>>>(
            b4, wo1t + l * WSL, bo1 + l * Dn, x, x, BSn, Dn, Dn, 128, 4);
        k_ln<<<gL, blk, 0, stream>>>(x, g1 + l * Dn, be1 + l * Dn, x);
        // ---- cross block: q,k from memory; v from x ----
        k_qkv8ph<<<gQ, blk8, 0, stream>>>(
            memb, x,
            wq2t + l * WSL, wk2t + l * WSL, wv2t + l * WSL,
            bq2 + l * Dn, bk2 + l * Dn, bv2 + l * Dn,
            b1, b2, b3);
        k_attn_mfma<<<gA, blkA, 0, stream>>>(b1, b2, b3, b4);
        k_gemm2ph<128, false, true><<<gW, blk, 0, stream>>>(
            b4, wo2t + l * WSL, bo2 + l * Dn, x, x, BSn, Dn, Dn, 128, 4);
        k_ln<<<gL, blk, 0, stream>>>(x, g2 + l * Dn, be2 + l * Dn, x);
        // ---- feed-forward ----
        k_gemm8ph<true><<<g8, blk8, 0, stream>>>(
            x, w1ft + l * WFL, b1f + l * Fn, h1, BSn, Fn, Dn, 8);
        k_gemm2ph<128, false, true><<<gW, blk, 0, stream>>>(
            h1, w2ft + l * WFL, b2f + l * Dn, x, x, BSn, Dn, Fn, 128, 4);
        k_ln<<<gL, blk, 0, stream>>>(x, gfp + l * Dn, bff + l * Dn, x);
    }

    k_final2<<<dim3(BSn / 64), blk, 0, stream>>>(x, wcat, bcat, timei, out);
}